// Round 3
// baseline (395.651 us; speedup 1.0000x reference)
//
#include <hip/hip_runtime.h>
#include <stdint.h>
#include <math.h>

#define B_ 4
#define E_ 1024
#define L_ 2048
#define H_ 16
#define DH_ 64
#define SCALE_ 0.03125f

typedef __bf16 bf16;
typedef __bf16 bf16x8 __attribute__((ext_vector_type(8)));
typedef __bf16 bf16x4 __attribute__((ext_vector_type(4)));
typedef float f32x4 __attribute__((ext_vector_type(4)));

__device__ __forceinline__ f32x4 mfma16(bf16x8 a, bf16x8 b, f32x4 c) {
  return __builtin_amdgcn_mfma_f32_16x16x32_bf16(a, b, c, 0, 0, 0);
}

// async global->LDS, 16B per lane. LDS dest = wave-uniform base + lane*16 (HW rule).
// CK pattern (amd_direct_load.hpp): addrspace pointers built via uintptr_t round-trip.
__device__ __forceinline__ void gl_lds16(const void* g, void* lds) {
  auto* lp = reinterpret_cast<__attribute__((address_space(3))) unsigned int*>(
      reinterpret_cast<uintptr_t>(lds));
  const auto* gp = reinterpret_cast<const __attribute__((address_space(1))) unsigned int*>(
      reinterpret_cast<uintptr_t>(g));
  __builtin_amdgcn_global_load_lds(gp, lp, 16, 0, 0);
}

// ---------------- transpose + f32->bf16 convert: out[c][r] = (bf16) in[r][c] ----------------
__global__ __launch_bounds__(256) void tconv(const float* __restrict__ in,
                                             bf16* __restrict__ out, int R, int C) {
  in  += (size_t)blockIdx.z * R * C;
  out += (size_t)blockIdx.z * R * C;
  __shared__ float t[32][33];
  const int r0 = blockIdx.x * 32, c0 = blockIdx.y * 32;
  const int lx = threadIdx.x & 31, ly = threadIdx.x >> 5;
#pragma unroll
  for (int q = 0; q < 4; q++)
    t[ly + q * 8][lx] = in[(size_t)(r0 + ly + q * 8) * C + c0 + lx];
  __syncthreads();
#pragma unroll
  for (int q = 0; q < 4; q++) {
    int c = ly + q * 8;
    out[(size_t)(c0 + c) * R + r0 + lx] = (bf16)t[lx][c];
  }
}

// ---------------- GEMM: C[m][n] = sum_k A[m][k] * Bt[n][k]  (both bf16, K-contiguous) -------
// EPI 0: write outT[b][n][m] (bf16) and outD[b][m][n] (bf16)    [kqvT + kqvD]
// EPI 1: write outF[b][m][n] = C + bias[m] (f32)
template <int EPI>
__global__ __launch_bounds__(256) void gemm_bt(const bf16* __restrict__ A,
                                               const bf16* __restrict__ Bt,
                                               bf16* __restrict__ outT,
                                               bf16* __restrict__ outD,
                                               float* __restrict__ outF,
                                               const float* __restrict__ bias) {
  constexpr int M = E_, N = L_, K = E_;
  const int bm = blockIdx.x, bn = blockIdx.y, b = blockIdx.z;
  __shared__ bf16 As[128 * 32];
  __shared__ bf16 Bs[128 * 32];
  const int tid = threadIdx.x, w = tid >> 6, l = tid & 63;
  const int wm = (w >> 1) << 6, wn = (w & 1) << 6;
  const bf16* Ap = A + (size_t)bm * 128 * K;
  const bf16* Bp = Bt + (size_t)b * N * K + (size_t)bn * 128 * K;
  f32x4 acc[4][4] = {};
  // staging: granule g (16B) -> LDS row g>>2 (64B rows), phys slot g&3; global slot = phys ^ f(row)
  const int g0 = (w * 2 + 0) * 64 + l, g1 = (w * 2 + 1) * 64 + l;
  const int r0 = g0 >> 2, s0 = (g0 & 3) ^ ((r0 >> 1) & 3);
  const int r1 = g1 >> 2, s1 = (g1 & 3) ^ ((r1 >> 1) & 3);
#pragma unroll 1
  for (int kt = 0; kt < K; kt += 32) {
    __syncthreads();
    gl_lds16(Ap + (size_t)r0 * K + kt + s0 * 8, As + g0 * 8);
    gl_lds16(Ap + (size_t)r1 * K + kt + s1 * 8, As + g1 * 8);
    gl_lds16(Bp + (size_t)r0 * K + kt + s0 * 8, Bs + g0 * 8);
    gl_lds16(Bp + (size_t)r1 * K + kt + s1 * 8, Bs + g1 * 8);
    asm volatile("s_waitcnt vmcnt(0)" ::: "memory");
    __syncthreads();
    bf16x8 af[4], bfr[4];
#pragma unroll
    for (int fm = 0; fm < 4; fm++) {
      int row = wm + fm * 16 + (l & 15);
      int gg = row * 4 + ((l >> 4) ^ ((row >> 1) & 3));
      af[fm] = *(const bf16x8*)(As + gg * 8);
    }
#pragma unroll
    for (int fn = 0; fn < 4; fn++) {
      int row = wn + fn * 16 + (l & 15);
      int gg = row * 4 + ((l >> 4) ^ ((row >> 1) & 3));
      bfr[fn] = *(const bf16x8*)(Bs + gg * 8);
    }
#pragma unroll
    for (int fm = 0; fm < 4; fm++)
#pragma unroll
      for (int fn = 0; fn < 4; fn++)
        acc[fm][fn] = mfma16(af[fm], bfr[fn], acc[fm][fn]);
  }
  const int cm = bm * 128 + wm, cn = bn * 128 + wn;
  if (EPI == 0) {
#pragma unroll
    for (int fn = 0; fn < 4; fn++) {
#pragma unroll
      for (int fm = 0; fm < 4; fm++) {
        int n = cn + fn * 16 + (l & 15);
        int m = cm + fm * 16 + ((l >> 4) << 2);
        f32x4 v = acc[fm][fn];
        bf16x4 pv = {(bf16)v[0], (bf16)v[1], (bf16)v[2], (bf16)v[3]};
        *(bf16x4*)(outT + (size_t)b * N * M + (size_t)n * M + m) = pv;
#pragma unroll
        for (int r = 0; r < 4; r++)
          outD[(size_t)b * M * N + (size_t)(m + r) * N + n] = pv[r];
      }
    }
  } else {
#pragma unroll
    for (int fm = 0; fm < 4; fm++) {
      int m = cm + fm * 16 + ((l >> 4) << 2);
#pragma unroll
      for (int r = 0; r < 4; r++) {
        float bv = bias[m + r];
#pragma unroll
        for (int fn = 0; fn < 4; fn++) {
          int n = cn + fn * 16 + (l & 15);
          outF[(size_t)b * M * N + (size_t)(m + r) * N + n] = acc[fm][fn][r] + bv;
        }
      }
    }
  }
}

// ---------------- flash attention (causal over keys i<=j, softmax over i) -------------------
// St[j,i] = sum_d Q[d,j] K[d,i]; A = Q rows from kqvT, Bt = K rows from kqvT
// t^T[j,d] = sum_i P'[j,i] V[d,i]; A = P' (LDS round-trip), Bt = V rows from kqvD
__global__ __launch_bounds__(256) void attn(const bf16* __restrict__ kqvT,
                                            const bf16* __restrict__ kqvD,
                                            bf16* __restrict__ tT) {
  const int jblk = blockIdx.x, h = blockIdx.y, b = blockIdx.z;
  const int tid = threadIdx.x, w = tid >> 6, l = tid & 63;
  const int j0 = jblk * 64 + w * 16;
  __shared__ bf16 Ks[64 * 64];
  __shared__ bf16 Vs[64 * 64];
  __shared__ bf16 Ps[4][16 * 64];
  const size_t bT = (size_t)b * L_ * E_;
  const size_t bD = (size_t)b * E_ * L_;
  bf16x8 qa[2];
  {
    size_t qoff = bT + (size_t)(j0 + (l & 15)) * E_ + h * 64 + ((l >> 4) << 3);
    qa[0] = *(const bf16x8*)(kqvT + qoff);
    qa[1] = *(const bf16x8*)(kqvT + qoff + 32);
  }
  float mrun[4], lrun[4];
  f32x4 tacc[4] = {};
#pragma unroll
  for (int r = 0; r < 4; r++) { mrun[r] = -INFINITY; lrun[r] = 0.f; }
  bf16* myPs = &Ps[w][0];
  const int gA = (w * 2 + 0) * 64 + l, gB = (w * 2 + 1) * 64 + l;
  const int rA = gA >> 3, sA = (gA & 7) ^ (rA & 7);
  const int rB = gB >> 3, sB = (gB & 7) ^ (rB & 7);
  const int nch = jblk + 1;
#pragma unroll 1
  for (int c = 0; c < nch; c++) {
    const int i0 = c * 64;
    __syncthreads();
    gl_lds16(kqvT + bT + (size_t)(i0 + rA) * E_ + h * 64 + sA * 8, Ks + gA * 8);
    gl_lds16(kqvT + bT + (size_t)(i0 + rB) * E_ + h * 64 + sB * 8, Ks + gB * 8);
    gl_lds16(kqvD + bD + (size_t)(h * 64 + rA) * L_ + i0 + sA * 8, Vs + gA * 8);
    gl_lds16(kqvD + bD + (size_t)(h * 64 + rB) * L_ + i0 + sB * 8, Vs + gB * 8);
    asm volatile("s_waitcnt vmcnt(0)" ::: "memory");
    __syncthreads();
    if (i0 <= j0 + 15) {
      f32x4 sacc[4];
#pragma unroll
      for (int fi = 0; fi < 4; fi++) {
        int row = fi * 16 + (l & 15);
        bf16x8 k0 = *(const bf16x8*)(Ks + row * 64 + (((l >> 4) ^ (row & 7)) << 3));
        bf16x8 k1 = *(const bf16x8*)(Ks + row * 64 + ((((l >> 4) + 4) ^ (row & 7)) << 3));
        f32x4 z = {};
        z = mfma16(qa[0], k0, z);
        z = mfma16(qa[1], k1, z);
        sacc[fi] = z;
      }
      float mx[4];
#pragma unroll
      for (int r = 0; r < 4; r++) mx[r] = -INFINITY;
      const int jrb = j0 + ((l >> 4) << 2);
#pragma unroll
      for (int fi = 0; fi < 4; fi++) {
        int i = i0 + fi * 16 + (l & 15);
#pragma unroll
        for (int r = 0; r < 4; r++) {
          float v = (i <= jrb + r) ? sacc[fi][r] * SCALE_ : -INFINITY;
          sacc[fi][r] = v;
          mx[r] = fmaxf(mx[r], v);
        }
      }
#pragma unroll
      for (int r = 0; r < 4; r++) {
        mx[r] = fmaxf(mx[r], __shfl_xor(mx[r], 1));
        mx[r] = fmaxf(mx[r], __shfl_xor(mx[r], 2));
        mx[r] = fmaxf(mx[r], __shfl_xor(mx[r], 4));
        mx[r] = fmaxf(mx[r], __shfl_xor(mx[r], 8));
      }
      float alpha[4], psum[4];
#pragma unroll
      for (int r = 0; r < 4; r++) {
        float mn = fmaxf(mrun[r], mx[r]);
        alpha[r] = (mn > -1e30f) ? __expf(mrun[r] - mn) : 1.0f;
        mrun[r] = mn;
        psum[r] = 0.f;
      }
#pragma unroll
      for (int fi = 0; fi < 4; fi++) {
        int icol = fi * 16 + (l & 15);
#pragma unroll
        for (int r = 0; r < 4; r++) {
          float v = sacc[fi][r];
          float p = (v > -1e30f) ? __expf(v - mrun[r]) : 0.f;
          psum[r] += p;
          int jl = ((l >> 4) << 2) + r;
          int slot = (icol >> 3) ^ (jl & 7);
          myPs[jl * 64 + slot * 8 + (icol & 7)] = (bf16)p;
        }
      }
#pragma unroll
      for (int r = 0; r < 4; r++) {
        psum[r] += __shfl_xor(psum[r], 1);
        psum[r] += __shfl_xor(psum[r], 2);
        psum[r] += __shfl_xor(psum[r], 4);
        psum[r] += __shfl_xor(psum[r], 8);
        lrun[r] = alpha[r] * lrun[r] + psum[r];
      }
#pragma unroll
      for (int fd = 0; fd < 4; fd++)
#pragma unroll
        for (int r = 0; r < 4; r++) tacc[fd][r] *= alpha[r];
      bf16x8 pa[2];
      {
        int jl = l & 15;
#pragma unroll
        for (int kc = 0; kc < 2; kc++)
          pa[kc] = *(const bf16x8*)(myPs + jl * 64 + (((kc * 4 + (l >> 4)) ^ (jl & 7)) << 3));
      }
#pragma unroll
      for (int fd = 0; fd < 4; fd++) {
        int row = fd * 16 + (l & 15);
#pragma unroll
        for (int kc = 0; kc < 2; kc++) {
          bf16x8 vf = *(const bf16x8*)(Vs + row * 64 + (((kc * 4 + (l >> 4)) ^ (row & 7)) << 3));
          tacc[fd] = mfma16(pa[kc], vf, tacc[fd]);
        }
      }
    }
  }
#pragma unroll
  for (int r = 0; r < 4; r++) {
    int j = j0 + ((l >> 4) << 2) + r;
    float inv = 1.0f / lrun[r];
#pragma unroll
    for (int fd = 0; fd < 4; fd++) {
      int d = fd * 16 + (l & 15);
      tT[bT + (size_t)j * E_ + h * 64 + d] = (bf16)(tacc[fd][r] * inv);
    }
  }
}

extern "C" void kernel_launch(void* const* d_in, const int* in_sizes, int n_in,
                              void* d_out, int out_size, void* d_ws, size_t ws_size,
                              hipStream_t stream) {
  const float* x     = (const float*)d_in[0];
  const float* Wqkv  = (const float*)d_in[1];
  const float* Wproj = (const float*)d_in[2];
  const float* bias  = (const float*)d_in[3];
  float* out = (float*)d_out;
  char* ws = (char*)d_ws;
  bf16* Wt_qkv  = (bf16*)ws;                         // 2 MB
  bf16* Wt_proj = (bf16*)(ws + (2ull << 20));        // 2 MB
  bf16* xT      = (bf16*)(ws + (4ull << 20));        // 16 MB (reused as tT)
  bf16* kqvT    = (bf16*)(ws + (20ull << 20));       // 16 MB
  bf16* kqvD    = (bf16*)(ws + (36ull << 20));       // 16 MB  -> total 52 MB
  bf16* tT      = xT;                                // alias: xT dead after gemm1

  tconv<<<dim3(32, 32, 1), 256, 0, stream>>>(Wqkv, Wt_qkv, E_, E_);
  tconv<<<dim3(32, 32, 1), 256, 0, stream>>>(Wproj, Wt_proj, E_, E_);
  tconv<<<dim3(32, 64, B_), 256, 0, stream>>>(x, xT, E_, L_);
  gemm_bt<0><<<dim3(8, 16, B_), 256, 0, stream>>>(Wt_qkv, xT, kqvT, kqvD,
                                                  (float*)nullptr, (const float*)nullptr);
  attn<<<dim3(L_ / 64, H_, B_), 256, 0, stream>>>(kqvT, kqvD, tT);
  gemm_bt<1><<<dim3(8, 16, B_), 256, 0, stream>>>(Wt_proj, tT, (bf16*)nullptr,
                                                  (bf16*)nullptr, out, bias);
}

// Round 4
// 355.855 us; speedup vs baseline: 1.1118x; 1.1118x over previous
//
#include <hip/hip_runtime.h>
#include <stdint.h>
#include <math.h>

#define B_ 4
#define E_ 1024
#define L_ 2048
#define H_ 16
#define DH_ 64
#define SCALE_ 0.03125f

typedef __bf16 bf16;
typedef __bf16 bf16x8 __attribute__((ext_vector_type(8)));
typedef __bf16 bf16x4 __attribute__((ext_vector_type(4)));
typedef float f32x4 __attribute__((ext_vector_type(4)));

__device__ __forceinline__ f32x4 mfma16(bf16x8 a, bf16x8 b, f32x4 c) {
  return __builtin_amdgcn_mfma_f32_16x16x32_bf16(a, b, c, 0, 0, 0);
}

// async global->LDS, 16B per lane. LDS dest = wave-uniform base + lane*16 (HW rule).
__device__ __forceinline__ void gl_lds16(const void* g, void* lds) {
  auto* lp = reinterpret_cast<__attribute__((address_space(3))) unsigned int*>(
      reinterpret_cast<uintptr_t>(lds));
  const auto* gp = reinterpret_cast<const __attribute__((address_space(1))) unsigned int*>(
      reinterpret_cast<uintptr_t>(g));
  __builtin_amdgcn_global_load_lds(gp, lp, 16, 0, 0);
}

// ---------------- transpose + f32->bf16 convert: out[c][r] = (bf16) in[r][c] ----------------
__global__ __launch_bounds__(256) void tconv(const float* __restrict__ in,
                                             bf16* __restrict__ out, int R, int C) {
  in  += (size_t)blockIdx.z * R * C;
  out += (size_t)blockIdx.z * R * C;
  __shared__ float t[32][33];
  const int r0 = blockIdx.x * 32, c0 = blockIdx.y * 32;
  const int lx = threadIdx.x & 31, ly = threadIdx.x >> 5;
#pragma unroll
  for (int q = 0; q < 4; q++)
    t[ly + q * 8][lx] = in[(size_t)(r0 + ly + q * 8) * C + c0 + lx];
  __syncthreads();
#pragma unroll
  for (int q = 0; q < 4; q++) {
    int c = ly + q * 8;
    out[(size_t)(c0 + c) * R + r0 + lx] = (bf16)t[lx][c];
  }
}

// ---------------- GEMM: C[m][n] = sum_k A[m][k] * Bt[n][k]  (both bf16, K-contiguous) -------
template <int EPI>
__global__ __launch_bounds__(256) void gemm_bt(const bf16* __restrict__ A,
                                               const bf16* __restrict__ Bt,
                                               bf16* __restrict__ outT,
                                               bf16* __restrict__ outD,
                                               float* __restrict__ outF,
                                               const float* __restrict__ bias) {
  constexpr int M = E_, N = L_, K = E_;
  const int bm = blockIdx.x, bn = blockIdx.y, b = blockIdx.z;
  __shared__ bf16 As[128 * 32];
  __shared__ bf16 Bs[128 * 32];
  const int tid = threadIdx.x, w = tid >> 6, l = tid & 63;
  const int wm = (w >> 1) << 6, wn = (w & 1) << 6;
  const bf16* Ap = A + (size_t)bm * 128 * K;
  const bf16* Bp = Bt + (size_t)b * N * K + (size_t)bn * 128 * K;
  f32x4 acc[4][4] = {};
  const int g0 = (w * 2 + 0) * 64 + l, g1 = (w * 2 + 1) * 64 + l;
  const int r0 = g0 >> 2, s0 = (g0 & 3) ^ ((r0 >> 1) & 3);
  const int r1 = g1 >> 2, s1 = (g1 & 3) ^ ((r1 >> 1) & 3);
#pragma unroll 1
  for (int kt = 0; kt < K; kt += 32) {
    __syncthreads();
    gl_lds16(Ap + (size_t)r0 * K + kt + s0 * 8, As + g0 * 8);
    gl_lds16(Ap + (size_t)r1 * K + kt + s1 * 8, As + g1 * 8);
    gl_lds16(Bp + (size_t)r0 * K + kt + s0 * 8, Bs + g0 * 8);
    gl_lds16(Bp + (size_t)r1 * K + kt + s1 * 8, Bs + g1 * 8);
    asm volatile("s_waitcnt vmcnt(0)" ::: "memory");
    __syncthreads();
    bf16x8 af[4], bfr[4];
#pragma unroll
    for (int fm = 0; fm < 4; fm++) {
      int row = wm + fm * 16 + (l & 15);
      int gg = row * 4 + ((l >> 4) ^ ((row >> 1) & 3));
      af[fm] = *(const bf16x8*)(As + gg * 8);
    }
#pragma unroll
    for (int fn = 0; fn < 4; fn++) {
      int row = wn + fn * 16 + (l & 15);
      int gg = row * 4 + ((l >> 4) ^ ((row >> 1) & 3));
      bfr[fn] = *(const bf16x8*)(Bs + gg * 8);
    }
#pragma unroll
    for (int fm = 0; fm < 4; fm++)
#pragma unroll
      for (int fn = 0; fn < 4; fn++)
        acc[fm][fn] = mfma16(af[fm], bfr[fn], acc[fm][fn]);
  }
  const int cm = bm * 128 + wm, cn = bn * 128 + wn;
  if (EPI == 0) {
#pragma unroll
    for (int fn = 0; fn < 4; fn++) {
#pragma unroll
      for (int fm = 0; fm < 4; fm++) {
        int n = cn + fn * 16 + (l & 15);
        int m = cm + fm * 16 + ((l >> 4) << 2);
        f32x4 v = acc[fm][fn];
        bf16x4 pv = {(bf16)v[0], (bf16)v[1], (bf16)v[2], (bf16)v[3]};
        *(bf16x4*)(outT + (size_t)b * N * M + (size_t)n * M + m) = pv;
#pragma unroll
        for (int r = 0; r < 4; r++)
          outD[(size_t)b * M * N + (size_t)(m + r) * N + n] = pv[r];
      }
    }
  } else {
#pragma unroll
    for (int fm = 0; fm < 4; fm++) {
      int m = cm + fm * 16 + ((l >> 4) << 2);
#pragma unroll
      for (int r = 0; r < 4; r++) {
        float bv = bias[m + r];
#pragma unroll
        for (int fn = 0; fn < 4; fn++) {
          int n = cn + fn * 16 + (l & 15);
          outF[(size_t)b * M * N + (size_t)(m + r) * N + n] = acc[fm][fn][r] + bv;
        }
      }
    }
  }
}

// ---------------- flash attention (causal over keys i<=j, softmax over i) -------------------
// Double-buffered K/V prefetch (T3 2-phase), mask on diagonal tile only, defer-max (T13).
__global__ __launch_bounds__(256) void attn(const bf16* __restrict__ kqvT,
                                            const bf16* __restrict__ kqvD,
                                            bf16* __restrict__ tT) {
  const int jblk = (int)gridDim.x - 1 - (int)blockIdx.x;  // heavy blocks first
  const int h = blockIdx.y, b = blockIdx.z;
  const int tid = threadIdx.x, w = tid >> 6, l = tid & 63;
  const int j0 = jblk * 64 + w * 16;
  __shared__ bf16 Ks[2][64 * 64];
  __shared__ bf16 Vs[2][64 * 64];
  __shared__ bf16 Ps[4][16 * 64];
  const size_t bT = (size_t)b * L_ * E_;
  const size_t bD = (size_t)b * E_ * L_;
  bf16x8 qa[2];
  {
    size_t qoff = bT + (size_t)(j0 + (l & 15)) * E_ + h * 64 + ((l >> 4) << 3);
    qa[0] = *(const bf16x8*)(kqvT + qoff);
    qa[1] = *(const bf16x8*)(kqvT + qoff + 32);
    // fold softmax scale into Q (2^-5: exact in bf16)
#pragma unroll
    for (int e = 0; e < 8; e++) {
      qa[0][e] = (bf16)((float)qa[0][e] * SCALE_);
      qa[1][e] = (bf16)((float)qa[1][e] * SCALE_);
    }
  }
  float mrun[4], lrun[4];
  f32x4 tacc[4] = {};
#pragma unroll
  for (int r = 0; r < 4; r++) { mrun[r] = -INFINITY; lrun[r] = 0.f; }
  bf16* myPs = &Ps[w][0];
  const int gA = (w * 2 + 0) * 64 + l, gB = (w * 2 + 1) * 64 + l;
  const int rA = gA >> 3, sA = (gA & 7) ^ (rA & 7);
  const int rB = gB >> 3, sB = (gB & 7) ^ (rB & 7);
  const int nch = jblk + 1;

#define STAGE(c, buf)                                                                  \
  do {                                                                                 \
    const int i0_ = (c) * 64;                                                          \
    gl_lds16(kqvT + bT + (size_t)(i0_ + rA) * E_ + h * 64 + sA * 8, &Ks[buf][gA * 8]); \
    gl_lds16(kqvT + bT + (size_t)(i0_ + rB) * E_ + h * 64 + sB * 8, &Ks[buf][gB * 8]); \
    gl_lds16(kqvD + bD + (size_t)(h * 64 + rA) * L_ + i0_ + sA * 8, &Vs[buf][gA * 8]); \
    gl_lds16(kqvD + bD + (size_t)(h * 64 + rB) * L_ + i0_ + sB * 8, &Vs[buf][gB * 8]); \
  } while (0)

  STAGE(0, 0);
  asm volatile("s_waitcnt vmcnt(0)" ::: "memory");
  __syncthreads();

#pragma unroll 1
  for (int c = 0; c < nch; c++) {
    const int cur = c & 1;
    if (c + 1 < nch) STAGE(c + 1, cur ^ 1);  // prefetch next tile (hides HBM latency)
    const int i0 = c * 64;
    const bf16* Kc = &Ks[cur][0];
    const bf16* Vc = &Vs[cur][0];
    // ---- QK^T (S[j,i], lane: i = fi*16 + (l&15), j = j0 + (l>>4)*4 + r) ----
    f32x4 sacc[4];
#pragma unroll
    for (int fi = 0; fi < 4; fi++) {
      int row = fi * 16 + (l & 15);
      bf16x8 k0 = *(const bf16x8*)(Kc + row * 64 + (((l >> 4) ^ (row & 7)) << 3));
      bf16x8 k1 = *(const bf16x8*)(Kc + row * 64 + ((((l >> 4) + 4) ^ (row & 7)) << 3));
      f32x4 z = {};
      z = mfma16(qa[0], k0, z);
      z = mfma16(qa[1], k1, z);
      sacc[fi] = z;
    }
    const int jrb = j0 + ((l >> 4) << 2);
    if (c == jblk) {  // diagonal tile: apply causal mask (i > j -> -inf)
#pragma unroll
      for (int fi = 0; fi < 4; fi++) {
        int i = i0 + fi * 16 + (l & 15);
#pragma unroll
        for (int r = 0; r < 4; r++)
          if (i > jrb + r) sacc[fi][r] = -INFINITY;
      }
    }
    // ---- tile row-max ----
    float mx[4];
#pragma unroll
    for (int r = 0; r < 4; r++)
      mx[r] = fmaxf(fmaxf(sacc[0][r], sacc[1][r]), fmaxf(sacc[2][r], sacc[3][r]));
#pragma unroll
    for (int r = 0; r < 4; r++) {
      mx[r] = fmaxf(mx[r], __shfl_xor(mx[r], 1));
      mx[r] = fmaxf(mx[r], __shfl_xor(mx[r], 2));
      mx[r] = fmaxf(mx[r], __shfl_xor(mx[r], 4));
      mx[r] = fmaxf(mx[r], __shfl_xor(mx[r], 8));
    }
    // ---- defer-max: rescale only if max grew by > 8 (T13) ----
    bool need = false;
#pragma unroll
    for (int r = 0; r < 4; r++) need |= (mx[r] > mrun[r] + 8.f);
    if (__any(need)) {
#pragma unroll
      for (int r = 0; r < 4; r++) {
        float mn = fmaxf(mrun[r], mx[r]);
        float a = __expf(mrun[r] - mn);  // exp(-inf)=0 on first tile
        lrun[r] *= a;
#pragma unroll
        for (int fd = 0; fd < 4; fd++) tacc[fd][r] *= a;
        mrun[r] = mn;
      }
    }
    // ---- P = exp(S - mrun), accumulate row-sum, store P to per-wave LDS ----
    float psum[4] = {0.f, 0.f, 0.f, 0.f};
#pragma unroll
    for (int fi = 0; fi < 4; fi++) {
      int icol = fi * 16 + (l & 15);
#pragma unroll
      for (int r = 0; r < 4; r++) {
        float p = __expf(sacc[fi][r] - mrun[r]);  // masked -> exp(-inf)=0
        psum[r] += p;
        int jl = ((l >> 4) << 2) + r;
        int slot = (icol >> 3) ^ (jl & 7);
        myPs[jl * 64 + slot * 8 + (icol & 7)] = (bf16)p;
      }
    }
#pragma unroll
    for (int r = 0; r < 4; r++) {
      psum[r] += __shfl_xor(psum[r], 1);
      psum[r] += __shfl_xor(psum[r], 2);
      psum[r] += __shfl_xor(psum[r], 4);
      psum[r] += __shfl_xor(psum[r], 8);
      lrun[r] += psum[r];
    }
    // ---- PV: tacc[j, d] += P[j, i] * V[d, i] ----
    bf16x8 pa[2];
    {
      int jl = l & 15;
#pragma unroll
      for (int kc = 0; kc < 2; kc++)
        pa[kc] = *(const bf16x8*)(myPs + jl * 64 + (((kc * 4 + (l >> 4)) ^ (jl & 7)) << 3));
    }
#pragma unroll
    for (int fd = 0; fd < 4; fd++) {
      int row = fd * 16 + (l & 15);
#pragma unroll
      for (int kc = 0; kc < 2; kc++) {
        bf16x8 vf = *(const bf16x8*)(Vc + row * 64 + (((kc * 4 + (l >> 4)) ^ (row & 7)) << 3));
        tacc[fd] = mfma16(pa[kc], vf, tacc[fd]);
      }
    }
    asm volatile("s_waitcnt vmcnt(0)" ::: "memory");  // prefetch landed
    __syncthreads();
  }
#undef STAGE
#pragma unroll
  for (int r = 0; r < 4; r++) {
    int j = j0 + ((l >> 4) << 2) + r;
    float inv = 1.0f / lrun[r];
#pragma unroll
    for (int fd = 0; fd < 4; fd++) {
      int d = fd * 16 + (l & 15);
      tT[bT + (size_t)j * E_ + h * 64 + d] = (bf16)(tacc[fd][r] * inv);
    }
  }
}

extern "C" void kernel_launch(void* const* d_in, const int* in_sizes, int n_in,
                              void* d_out, int out_size, void* d_ws, size_t ws_size,
                              hipStream_t stream) {
  const float* x     = (const float*)d_in[0];
  const float* Wqkv  = (const float*)d_in[1];
  const float* Wproj = (const float*)d_in[2];
  const float* bias  = (const float*)d_in[3];
  float* out = (float*)d_out;
  char* ws = (char*)d_ws;
  bf16* Wt_qkv  = (bf16*)ws;                         // 2 MB
  bf16* Wt_proj = (bf16*)(ws + (2ull << 20));        // 2 MB
  bf16* xT      = (bf16*)(ws + (4ull << 20));        // 16 MB (reused as tT)
  bf16* kqvT    = (bf16*)(ws + (20ull << 20));       // 16 MB
  bf16* kqvD    = (bf16*)(ws + (36ull << 20));       // 16 MB  -> total 52 MB
  bf16* tT      = xT;                                // alias: xT dead after gemm1

  tconv<<<dim3(32, 32, 1), 256, 0, stream>>>(Wqkv, Wt_qkv, E_, E_);
  tconv<<<dim3(32, 32, 1), 256, 0, stream>>>(Wproj, Wt_proj, E_, E_);
  tconv<<<dim3(32, 64, B_), 256, 0, stream>>>(x, xT, E_, L_);
  gemm_bt<0><<<dim3(8, 16, B_), 256, 0, stream>>>(Wt_qkv, xT, kqvT, kqvD,
                                                  (float*)nullptr, (const float*)nullptr);
  attn<<<dim3(L_ / 64, H_, B_), 256, 0, stream>>>(kqvT, kqvD, tT);
  gemm_bt<1><<<dim3(8, 16, B_), 256, 0, stream>>>(Wt_proj, tT, (bf16*)nullptr,
                                                  (bf16*)nullptr, out, bias);
}

// Round 5
// 228.611 us; speedup vs baseline: 1.7307x; 1.5566x over previous
//
#include <hip/hip_runtime.h>
#include <stdint.h>
#include <math.h>

#define B_ 4
#define E_ 1024
#define L_ 2048
#define H_ 16
#define DH_ 64
#define SCALE_ 0.03125f

typedef __bf16 bf16;
typedef __bf16 bf16x8 __attribute__((ext_vector_type(8)));
typedef __bf16 bf16x4 __attribute__((ext_vector_type(4)));
typedef float f32x4 __attribute__((ext_vector_type(4)));

__device__ __forceinline__ f32x4 mfma16(bf16x8 a, bf16x8 b, f32x4 c) {
  return __builtin_amdgcn_mfma_f32_16x16x32_bf16(a, b, c, 0, 0, 0);
}

// async global->LDS, 16B per lane. LDS dest = wave-uniform base + lane*16 (HW rule).
__device__ __forceinline__ void gl_lds16(const void* g, void* lds) {
  auto* lp = reinterpret_cast<__attribute__((address_space(3))) unsigned int*>(
      reinterpret_cast<uintptr_t>(lds));
  const auto* gp = reinterpret_cast<const __attribute__((address_space(1))) unsigned int*>(
      reinterpret_cast<uintptr_t>(g));
  __builtin_amdgcn_global_load_lds(gp, lp, 16, 0, 0);
}

// ---------------- transpose + f32->bf16 convert: out[c][r] = (bf16) in[r][c] ----------------
__global__ __launch_bounds__(256) void tconv(const float* __restrict__ in,
                                             bf16* __restrict__ out, int R, int C) {
  in  += (size_t)blockIdx.z * R * C;
  out += (size_t)blockIdx.z * R * C;
  __shared__ float t[32][33];
  const int r0 = blockIdx.x * 32, c0 = blockIdx.y * 32;
  const int lx = threadIdx.x & 31, ly = threadIdx.x >> 5;
#pragma unroll
  for (int q = 0; q < 4; q++)
    t[ly + q * 8][lx] = in[(size_t)(r0 + ly + q * 8) * C + c0 + lx];
  __syncthreads();
#pragma unroll
  for (int q = 0; q < 4; q++) {
    int c = ly + q * 8;
    out[(size_t)(c0 + c) * R + r0 + lx] = (bf16)t[lx][c];
  }
}

// ---------------- GEMM: C[m][n] = sum_k A[m][k] * Bt[n][k]  (both bf16, K-contiguous) -------
template <int EPI>
__global__ __launch_bounds__(256) void gemm_bt(const bf16* __restrict__ A,
                                               const bf16* __restrict__ Bt,
                                               bf16* __restrict__ outT,
                                               bf16* __restrict__ outD,
                                               float* __restrict__ outF,
                                               const float* __restrict__ bias) {
  constexpr int M = E_, N = L_, K = E_;
  const int bm = blockIdx.x, bn = blockIdx.y, b = blockIdx.z;
  __shared__ bf16 As[128 * 32];
  __shared__ bf16 Bs[128 * 32];
  const int tid = threadIdx.x, w = tid >> 6, l = tid & 63;
  const int wm = (w >> 1) << 6, wn = (w & 1) << 6;
  const bf16* Ap = A + (size_t)bm * 128 * K;
  const bf16* Bp = Bt + (size_t)b * N * K + (size_t)bn * 128 * K;
  f32x4 acc[4][4] = {};
  const int g0 = (w * 2 + 0) * 64 + l, g1 = (w * 2 + 1) * 64 + l;
  const int r0 = g0 >> 2, s0 = (g0 & 3) ^ ((r0 >> 1) & 3);
  const int r1 = g1 >> 2, s1 = (g1 & 3) ^ ((r1 >> 1) & 3);
#pragma unroll 1
  for (int kt = 0; kt < K; kt += 32) {
    __syncthreads();
    gl_lds16(Ap + (size_t)r0 * K + kt + s0 * 8, As + g0 * 8);
    gl_lds16(Ap + (size_t)r1 * K + kt + s1 * 8, As + g1 * 8);
    gl_lds16(Bp + (size_t)r0 * K + kt + s0 * 8, Bs + g0 * 8);
    gl_lds16(Bp + (size_t)r1 * K + kt + s1 * 8, Bs + g1 * 8);
    asm volatile("s_waitcnt vmcnt(0)" ::: "memory");
    __syncthreads();
    bf16x8 af[4], bfr[4];
#pragma unroll
    for (int fm = 0; fm < 4; fm++) {
      int row = wm + fm * 16 + (l & 15);
      int gg = row * 4 + ((l >> 4) ^ ((row >> 1) & 3));
      af[fm] = *(const bf16x8*)(As + gg * 8);
    }
#pragma unroll
    for (int fn = 0; fn < 4; fn++) {
      int row = wn + fn * 16 + (l & 15);
      int gg = row * 4 + ((l >> 4) ^ ((row >> 1) & 3));
      bfr[fn] = *(const bf16x8*)(Bs + gg * 8);
    }
#pragma unroll
    for (int fm = 0; fm < 4; fm++)
#pragma unroll
      for (int fn = 0; fn < 4; fn++)
        acc[fm][fn] = mfma16(af[fm], bfr[fn], acc[fm][fn]);
  }
  const int cm = bm * 128 + wm, cn = bn * 128 + wn;
  if (EPI == 0) {
#pragma unroll
    for (int fn = 0; fn < 4; fn++) {
#pragma unroll
      for (int fm = 0; fm < 4; fm++) {
        int n = cn + fn * 16 + (l & 15);
        int m = cm + fm * 16 + ((l >> 4) << 2);
        f32x4 v = acc[fm][fn];
        bf16x4 pv = {(bf16)v[0], (bf16)v[1], (bf16)v[2], (bf16)v[3]};
        *(bf16x4*)(outT + (size_t)b * N * M + (size_t)n * M + m) = pv;
#pragma unroll
        for (int r = 0; r < 4; r++)
          outD[(size_t)b * M * N + (size_t)(m + r) * N + n] = pv[r];
      }
    }
  } else {
#pragma unroll
    for (int fm = 0; fm < 4; fm++) {
      int m = cm + fm * 16 + ((l >> 4) << 2);
#pragma unroll
      for (int r = 0; r < 4; r++) {
        float bv = bias[m + r];
#pragma unroll
        for (int fn = 0; fn < 4; fn++) {
          int n = cn + fn * 16 + (l & 15);
          outF[(size_t)b * M * N + (size_t)(m + r) * N + n] = acc[fm][fn][r] + bv;
        }
      }
    }
  }
}

// ---------------- flash attention (causal over keys i<=j, softmax over i) -------------------
// QBLK=128 (8 waves x 16 rows), dbuf K/V prefetch, zero in-loop cross-lane reduces:
//  - running max fixed at 0 with in-register overflow guard (cold rescale path, THR=8)
//  - row-sum kept as per-lane partials, single shuffle reduce after the loop
__global__ __launch_bounds__(512) void attn(const bf16* __restrict__ kqvT,
                                            const bf16* __restrict__ kqvD,
                                            bf16* __restrict__ tT) {
  // true heavy-first dispatch: linear id -> (qb, h, b), qb=15 (32 iters) first
  const int linear = (int)blockIdx.x + 16 * ((int)blockIdx.y + 16 * (int)blockIdx.z);
  const int qb = 15 - (linear >> 6);
  const int h = linear & 15, b = (linear >> 4) & 3;
  const int tid = threadIdx.x, w = tid >> 6, l = tid & 63;
  const int j0 = qb * 128 + w * 16;
  __shared__ bf16 Ks[2][64 * 64];
  __shared__ bf16 Vs[2][64 * 64];
  __shared__ bf16 Ps[8][16 * 64];
  const size_t bT = (size_t)b * L_ * E_;
  const size_t bD = (size_t)b * E_ * L_;
  bf16x8 qa[2];
  {
    size_t qoff = bT + (size_t)(j0 + (l & 15)) * E_ + h * 64 + ((l >> 4) << 3);
    qa[0] = *(const bf16x8*)(kqvT + qoff);
    qa[1] = *(const bf16x8*)(kqvT + qoff + 32);
#pragma unroll
    for (int e = 0; e < 8; e++) {  // fold scale into Q (2^-5 exact in bf16)
      qa[0][e] = (bf16)((float)qa[0][e] * SCALE_);
      qa[1][e] = (bf16)((float)qa[1][e] * SCALE_);
    }
  }
  float mrun[4] = {0.f, 0.f, 0.f, 0.f};   // deferred max, guard at +8
  float lsum[4] = {0.f, 0.f, 0.f, 0.f};   // per-lane partial row-sums
  f32x4 tacc[4] = {};
  bf16* myPs = &Ps[w][0];
  // staging: 512 lanes x 1 granule(16B) each per buffer (K and V)
  const int g = w * 64 + l;
  const int rS = g >> 3, sS = (g & 7) ^ (rS & 7);
  const int nch = 2 * (qb + 1);

#define STAGE(c, buf)                                                                  \
  do {                                                                                 \
    const int i0_ = (c) * 64;                                                          \
    gl_lds16(kqvT + bT + (size_t)(i0_ + rS) * E_ + h * 64 + sS * 8, &Ks[buf][g * 8]);  \
    gl_lds16(kqvD + bD + (size_t)(h * 64 + rS) * L_ + i0_ + sS * 8, &Vs[buf][g * 8]);  \
  } while (0)

  STAGE(0, 0);
  asm volatile("s_waitcnt vmcnt(0)" ::: "memory");
  __syncthreads();

#pragma unroll 1
  for (int c = 0; c < nch; c++) {
    const int cur = c & 1;
    if (c + 1 < nch) STAGE(c + 1, cur ^ 1);  // prefetch next tile
    const int i0 = c * 64;
    const bf16* Kc = &Ks[cur][0];
    const bf16* Vc = &Vs[cur][0];
    if (i0 <= j0 + 15) {  // wave-uniform: skip fully-masked tiles
      // ---- QK^T ----
      f32x4 sacc[4];
      __builtin_amdgcn_s_setprio(1);
#pragma unroll
      for (int fi = 0; fi < 4; fi++) {
        int row = fi * 16 + (l & 15);
        bf16x8 k0 = *(const bf16x8*)(Kc + row * 64 + (((l >> 4) ^ (row & 7)) << 3));
        bf16x8 k1 = *(const bf16x8*)(Kc + row * 64 + ((((l >> 4) + 4) ^ (row & 7)) << 3));
        f32x4 z = {};
        z = mfma16(qa[0], k0, z);
        z = mfma16(qa[1], k1, z);
        sacc[fi] = z;
      }
      __builtin_amdgcn_s_setprio(0);
      const int jrb = j0 + ((l >> 4) << 2);
      if (i0 + 63 > j0) {  // tile touches the diagonal: causal mask
#pragma unroll
        for (int fi = 0; fi < 4; fi++) {
          int i = i0 + fi * 16 + (l & 15);
#pragma unroll
          for (int r = 0; r < 4; r++)
            if (i > jrb + r) sacc[fi][r] = -INFINITY;
        }
      }
      // ---- overflow guard (no cross-lane ops in hot path) ----
      bool ov = false;
#pragma unroll
      for (int fi = 0; fi < 4; fi++)
#pragma unroll
        for (int r = 0; r < 4; r++) ov |= (sacc[fi][r] > mrun[r] + 8.f);
      if (__any(ov)) {  // cold: true rescale (never taken for this data)
        float mx[4];
#pragma unroll
        for (int r = 0; r < 4; r++)
          mx[r] = fmaxf(fmaxf(sacc[0][r], sacc[1][r]), fmaxf(sacc[2][r], sacc[3][r]));
#pragma unroll
        for (int r = 0; r < 4; r++) {
          mx[r] = fmaxf(mx[r], __shfl_xor(mx[r], 1));
          mx[r] = fmaxf(mx[r], __shfl_xor(mx[r], 2));
          mx[r] = fmaxf(mx[r], __shfl_xor(mx[r], 4));
          mx[r] = fmaxf(mx[r], __shfl_xor(mx[r], 8));
        }
#pragma unroll
        for (int r = 0; r < 4; r++) {
          float mn = fmaxf(mrun[r], mx[r]);
          float a = __expf(mrun[r] - mn);
          lsum[r] *= a;
#pragma unroll
          for (int fd = 0; fd < 4; fd++) tacc[fd][r] *= a;
          mrun[r] = mn;
        }
      }
      // ---- P = exp(S - mrun), per-lane partial sums, P -> per-wave LDS ----
#pragma unroll
      for (int fi = 0; fi < 4; fi++) {
        int icol = fi * 16 + (l & 15);
#pragma unroll
        for (int r = 0; r < 4; r++) {
          float p = __expf(sacc[fi][r] - mrun[r]);
          lsum[r] += p;
          int jl = ((l >> 4) << 2) + r;
          int slot = (icol >> 3) ^ (jl & 7);
          myPs[jl * 64 + slot * 8 + (icol & 7)] = (bf16)p;
        }
      }
      // ---- PV ----
      bf16x8 pa[2];
      {
        int jl = l & 15;
#pragma unroll
        for (int kc = 0; kc < 2; kc++)
          pa[kc] = *(const bf16x8*)(myPs + jl * 64 + (((kc * 4 + (l >> 4)) ^ (jl & 7)) << 3));
      }
      __builtin_amdgcn_s_setprio(1);
#pragma unroll
      for (int fd = 0; fd < 4; fd++) {
        int row = fd * 16 + (l & 15);
#pragma unroll
        for (int kc = 0; kc < 2; kc++) {
          bf16x8 vf = *(const bf16x8*)(Vc + row * 64 + (((kc * 4 + (l >> 4)) ^ (row & 7)) << 3));
          tacc[fd] = mfma16(pa[kc], vf, tacc[fd]);
        }
      }
      __builtin_amdgcn_s_setprio(0);
    }
    asm volatile("s_waitcnt vmcnt(0)" ::: "memory");  // prefetch landed
    __syncthreads();
  }
#undef STAGE
  // ---- single deferred row-sum reduce ----
#pragma unroll
  for (int r = 0; r < 4; r++) {
    lsum[r] += __shfl_xor(lsum[r], 1);
    lsum[r] += __shfl_xor(lsum[r], 2);
    lsum[r] += __shfl_xor(lsum[r], 4);
    lsum[r] += __shfl_xor(lsum[r], 8);
  }
#pragma unroll
  for (int r = 0; r < 4; r++) {
    int j = j0 + ((l >> 4) << 2) + r;
    float inv = 1.0f / lsum[r];
#pragma unroll
    for (int fd = 0; fd < 4; fd++) {
      int d = fd * 16 + (l & 15);
      tT[bT + (size_t)j * E_ + h * 64 + d] = (bf16)(tacc[fd][r] * inv);
    }
  }
}

extern "C" void kernel_launch(void* const* d_in, const int* in_sizes, int n_in,
                              void* d_out, int out_size, void* d_ws, size_t ws_size,
                              hipStream_t stream) {
  const float* x     = (const float*)d_in[0];
  const float* Wqkv  = (const float*)d_in[1];
  const float* Wproj = (const float*)d_in[2];
  const float* bias  = (const float*)d_in[3];
  float* out = (float*)d_out;
  char* ws = (char*)d_ws;
  bf16* Wt_qkv  = (bf16*)ws;                         // 2 MB
  bf16* Wt_proj = (bf16*)(ws + (2ull << 20));        // 2 MB
  bf16* xT      = (bf16*)(ws + (4ull << 20));        // 16 MB (reused as tT)
  bf16* kqvT    = (bf16*)(ws + (20ull << 20));       // 16 MB
  bf16* kqvD    = (bf16*)(ws + (36ull << 20));       // 16 MB  -> total 52 MB
  bf16* tT      = xT;                                // alias: xT dead after gemm1

  tconv<<<dim3(32, 32, 1), 256, 0, stream>>>(Wqkv, Wt_qkv, E_, E_);
  tconv<<<dim3(32, 32, 1), 256, 0, stream>>>(Wproj, Wt_proj, E_, E_);
  tconv<<<dim3(32, 64, B_), 256, 0, stream>>>(x, xT, E_, L_);
  gemm_bt<0><<<dim3(8, 16, B_), 256, 0, stream>>>(Wt_qkv, xT, kqvT, kqvD,
                                                  (float*)nullptr, (const float*)nullptr);
  attn<<<dim3(16, 16, B_), 512, 0, stream>>>(kqvT, kqvD, tT);
  gemm_bt<1><<<dim3(8, 16, B_), 256, 0, stream>>>(Wt_proj, tT, (bf16*)nullptr,
                                                  (bf16*)nullptr, out, bias);
}

// Round 6
// 213.042 us; speedup vs baseline: 1.8572x; 1.0731x over previous
//
#include <hip/hip_runtime.h>
#include <stdint.h>
#include <math.h>

#define B_ 4
#define E_ 1024
#define L_ 2048
#define H_ 16
#define DH_ 64
#define SCALE_ 0.03125f

typedef __bf16 bf16;
typedef __bf16 bf16x8 __attribute__((ext_vector_type(8)));
typedef __bf16 bf16x4 __attribute__((ext_vector_type(4)));
typedef float f32x4 __attribute__((ext_vector_type(4)));

__device__ __forceinline__ f32x4 mfma16(bf16x8 a, bf16x8 b, f32x4 c) {
  return __builtin_amdgcn_mfma_f32_16x16x32_bf16(a, b, c, 0, 0, 0);
}

// async global->LDS, 16B per lane. LDS dest = wave-uniform base + lane*16 (HW rule).
__device__ __forceinline__ void gl_lds16(const void* g, void* lds) {
  auto* lp = reinterpret_cast<__attribute__((address_space(3))) unsigned int*>(
      reinterpret_cast<uintptr_t>(lds));
  const auto* gp = reinterpret_cast<const __attribute__((address_space(1))) unsigned int*>(
      reinterpret_cast<uintptr_t>(g));
  __builtin_amdgcn_global_load_lds(gp, lp, 16, 0, 0);
}

// ---------------- transpose + f32->bf16 convert: out[c][r] = (bf16) in[r][c] ----------------
__global__ __launch_bounds__(256) void tconv(const float* __restrict__ in,
                                             bf16* __restrict__ out, int R, int C) {
  in  += (size_t)blockIdx.z * R * C;
  out += (size_t)blockIdx.z * R * C;
  __shared__ float t[32][33];
  const int r0 = blockIdx.x * 32, c0 = blockIdx.y * 32;
  const int lx = threadIdx.x & 31, ly = threadIdx.x >> 5;
#pragma unroll
  for (int q = 0; q < 4; q++)
    t[ly + q * 8][lx] = in[(size_t)(r0 + ly + q * 8) * C + c0 + lx];
  __syncthreads();
#pragma unroll
  for (int q = 0; q < 4; q++) {
    int c = ly + q * 8;
    out[(size_t)(c0 + c) * R + r0 + lx] = (bf16)t[lx][c];
  }
}

// both weight transposes in one launch (z selects the pair)
__global__ __launch_bounds__(256) void wconv(const float* __restrict__ in0,
                                             const float* __restrict__ in1,
                                             bf16* __restrict__ out0,
                                             bf16* __restrict__ out1) {
  const float* in = blockIdx.z ? in1 : in0;
  bf16* out = blockIdx.z ? out1 : out0;
  __shared__ float t[32][33];
  const int r0 = blockIdx.x * 32, c0 = blockIdx.y * 32;
  const int lx = threadIdx.x & 31, ly = threadIdx.x >> 5;
#pragma unroll
  for (int q = 0; q < 4; q++)
    t[ly + q * 8][lx] = in[(size_t)(r0 + ly + q * 8) * E_ + c0 + lx];
  __syncthreads();
#pragma unroll
  for (int q = 0; q < 4; q++) {
    int c = ly + q * 8;
    out[(size_t)(c0 + c) * E_ + r0 + lx] = (bf16)t[lx][c];
  }
}

// ---------------- GEMM: C[m][n] = sum_k A[m][k] * Bt[n][k]  (both bf16, K-contiguous) -------
// 2-phase double-buffered K-loop (T3 minimum recipe): prefetch kt+1 before computing kt.
template <int EPI>
__global__ __launch_bounds__(256) void gemm_bt(const bf16* __restrict__ A,
                                               const bf16* __restrict__ Bt,
                                               bf16* __restrict__ outT,
                                               bf16* __restrict__ outD,
                                               float* __restrict__ outF,
                                               const float* __restrict__ bias) {
  constexpr int M = E_, N = L_, K = E_;
  constexpr int NIT = K / 32;
  const int bm = blockIdx.x, bn = blockIdx.y, b = blockIdx.z;
  __shared__ bf16 As[2][128 * 32];
  __shared__ bf16 Bs[2][128 * 32];
  const int tid = threadIdx.x, w = tid >> 6, l = tid & 63;
  const int wm = (w >> 1) << 6, wn = (w & 1) << 6;
  const bf16* Ap = A + (size_t)bm * 128 * K;
  const bf16* Bp = Bt + (size_t)b * N * K + (size_t)bn * 128 * K;
  f32x4 acc[4][4] = {};
  const int g0 = (w * 2 + 0) * 64 + l, g1 = (w * 2 + 1) * 64 + l;
  const int r0 = g0 >> 2, s0 = (g0 & 3) ^ ((r0 >> 1) & 3);
  const int r1 = g1 >> 2, s1 = (g1 & 3) ^ ((r1 >> 1) & 3);

#define STAGE_G(kt_, buf)                                              \
  do {                                                                 \
    gl_lds16(Ap + (size_t)r0 * K + (kt_) + s0 * 8, &As[buf][g0 * 8]);  \
    gl_lds16(Ap + (size_t)r1 * K + (kt_) + s1 * 8, &As[buf][g1 * 8]);  \
    gl_lds16(Bp + (size_t)r0 * K + (kt_) + s0 * 8, &Bs[buf][g0 * 8]);  \
    gl_lds16(Bp + (size_t)r1 * K + (kt_) + s1 * 8, &Bs[buf][g1 * 8]);  \
  } while (0)

  STAGE_G(0, 0);
  asm volatile("s_waitcnt vmcnt(0)" ::: "memory");
  __syncthreads();
#pragma unroll 1
  for (int it = 0; it < NIT; it++) {
    const int cur = it & 1;
    if (it + 1 < NIT) STAGE_G((it + 1) * 32, cur ^ 1);  // prefetch next K-tile
    bf16x8 af[4], bfr[4];
#pragma unroll
    for (int fm = 0; fm < 4; fm++) {
      int row = wm + fm * 16 + (l & 15);
      int gg = row * 4 + ((l >> 4) ^ ((row >> 1) & 3));
      af[fm] = *(const bf16x8*)(&As[cur][gg * 8]);
    }
#pragma unroll
    for (int fn = 0; fn < 4; fn++) {
      int row = wn + fn * 16 + (l & 15);
      int gg = row * 4 + ((l >> 4) ^ ((row >> 1) & 3));
      bfr[fn] = *(const bf16x8*)(&Bs[cur][gg * 8]);
    }
#pragma unroll
    for (int fm = 0; fm < 4; fm++)
#pragma unroll
      for (int fn = 0; fn < 4; fn++)
        acc[fm][fn] = mfma16(af[fm], bfr[fn], acc[fm][fn]);
    asm volatile("s_waitcnt vmcnt(0)" ::: "memory");  // prefetch landed
    __syncthreads();
  }
#undef STAGE_G
  const int cm = bm * 128 + wm, cn = bn * 128 + wn;
  if (EPI == 0) {
#pragma unroll
    for (int fn = 0; fn < 4; fn++) {
#pragma unroll
      for (int fm = 0; fm < 4; fm++) {
        int n = cn + fn * 16 + (l & 15);
        int m = cm + fm * 16 + ((l >> 4) << 2);
        f32x4 v = acc[fm][fn];
        bf16x4 pv = {(bf16)v[0], (bf16)v[1], (bf16)v[2], (bf16)v[3]};
        *(bf16x4*)(outT + (size_t)b * N * M + (size_t)n * M + m) = pv;
#pragma unroll
        for (int r = 0; r < 4; r++)
          outD[(size_t)b * M * N + (size_t)(m + r) * N + n] = pv[r];
      }
    }
  } else {
#pragma unroll
    for (int fm = 0; fm < 4; fm++) {
      int m = cm + fm * 16 + ((l >> 4) << 2);
#pragma unroll
      for (int r = 0; r < 4; r++) {
        float bv = bias[m + r];
#pragma unroll
        for (int fn = 0; fn < 4; fn++) {
          int n = cn + fn * 16 + (l & 15);
          outF[(size_t)b * M * N + (size_t)(m + r) * N + n] = acc[fm][fn][r] + bv;
        }
      }
    }
  }
}

// ---------------- flash attention (causal over keys i<=j, softmax over i) -------------------
// QBLK=128 (8 waves x 16 rows), dbuf K/V prefetch, zero in-loop cross-lane reduces.
__global__ __launch_bounds__(512) void attn(const bf16* __restrict__ kqvT,
                                            const bf16* __restrict__ kqvD,
                                            bf16* __restrict__ tT) {
  const int linear = (int)blockIdx.x + 16 * ((int)blockIdx.y + 16 * (int)blockIdx.z);
  const int qb = 15 - (linear >> 6);
  const int h = linear & 15, b = (linear >> 4) & 3;
  const int tid = threadIdx.x, w = tid >> 6, l = tid & 63;
  const int j0 = qb * 128 + w * 16;
  __shared__ bf16 Ks[2][64 * 64];
  __shared__ bf16 Vs[2][64 * 64];
  __shared__ bf16 Ps[8][16 * 64];
  const size_t bT = (size_t)b * L_ * E_;
  const size_t bD = (size_t)b * E_ * L_;
  bf16x8 qa[2];
  {
    size_t qoff = bT + (size_t)(j0 + (l & 15)) * E_ + h * 64 + ((l >> 4) << 3);
    qa[0] = *(const bf16x8*)(kqvT + qoff);
    qa[1] = *(const bf16x8*)(kqvT + qoff + 32);
#pragma unroll
    for (int e = 0; e < 8; e++) {  // fold scale into Q (2^-5 exact in bf16)
      qa[0][e] = (bf16)((float)qa[0][e] * SCALE_);
      qa[1][e] = (bf16)((float)qa[1][e] * SCALE_);
    }
  }
  float mrun[4] = {0.f, 0.f, 0.f, 0.f};   // deferred max, guard at +8
  float lsum[4] = {0.f, 0.f, 0.f, 0.f};   // per-lane partial row-sums
  f32x4 tacc[4] = {};
  bf16* myPs = &Ps[w][0];
  const int g = w * 64 + l;
  const int rS = g >> 3, sS = (g & 7) ^ (rS & 7);
  const int nch = 2 * (qb + 1);

#define STAGE(c, buf)                                                                  \
  do {                                                                                 \
    const int i0_ = (c) * 64;                                                          \
    gl_lds16(kqvT + bT + (size_t)(i0_ + rS) * E_ + h * 64 + sS * 8, &Ks[buf][g * 8]);  \
    gl_lds16(kqvD + bD + (size_t)(h * 64 + rS) * L_ + i0_ + sS * 8, &Vs[buf][g * 8]);  \
  } while (0)

  STAGE(0, 0);
  asm volatile("s_waitcnt vmcnt(0)" ::: "memory");
  __syncthreads();

#pragma unroll 1
  for (int c = 0; c < nch; c++) {
    const int cur = c & 1;
    if (c + 1 < nch) STAGE(c + 1, cur ^ 1);  // prefetch next tile
    const int i0 = c * 64;
    const bf16* Kc = &Ks[cur][0];
    const bf16* Vc = &Vs[cur][0];
    if (i0 <= j0 + 15) {  // wave-uniform: skip fully-masked tiles
      f32x4 sacc[4];
      __builtin_amdgcn_s_setprio(1);
#pragma unroll
      for (int fi = 0; fi < 4; fi++) {
        int row = fi * 16 + (l & 15);
        bf16x8 k0 = *(const bf16x8*)(Kc + row * 64 + (((l >> 4) ^ (row & 7)) << 3));
        bf16x8 k1 = *(const bf16x8*)(Kc + row * 64 + ((((l >> 4) + 4) ^ (row & 7)) << 3));
        f32x4 z = {};
        z = mfma16(qa[0], k0, z);
        z = mfma16(qa[1], k1, z);
        sacc[fi] = z;
      }
      __builtin_amdgcn_s_setprio(0);
      const int jrb = j0 + ((l >> 4) << 2);
      if (i0 + 63 > j0) {  // tile touches the diagonal: causal mask
#pragma unroll
        for (int fi = 0; fi < 4; fi++) {
          int i = i0 + fi * 16 + (l & 15);
#pragma unroll
          for (int r = 0; r < 4; r++)
            if (i > jrb + r) sacc[fi][r] = -INFINITY;
        }
      }
      bool ov = false;
#pragma unroll
      for (int fi = 0; fi < 4; fi++)
#pragma unroll
        for (int r = 0; r < 4; r++) ov |= (sacc[fi][r] > mrun[r] + 8.f);
      if (__any(ov)) {  // cold: true rescale (never taken for this data)
        float mx[4];
#pragma unroll
        for (int r = 0; r < 4; r++)
          mx[r] = fmaxf(fmaxf(sacc[0][r], sacc[1][r]), fmaxf(sacc[2][r], sacc[3][r]));
#pragma unroll
        for (int r = 0; r < 4; r++) {
          mx[r] = fmaxf(mx[r], __shfl_xor(mx[r], 1));
          mx[r] = fmaxf(mx[r], __shfl_xor(mx[r], 2));
          mx[r] = fmaxf(mx[r], __shfl_xor(mx[r], 4));
          mx[r] = fmaxf(mx[r], __shfl_xor(mx[r], 8));
        }
#pragma unroll
        for (int r = 0; r < 4; r++) {
          float mn = fmaxf(mrun[r], mx[r]);
          float a = __expf(mrun[r] - mn);
          lsum[r] *= a;
#pragma unroll
          for (int fd = 0; fd < 4; fd++) tacc[fd][r] *= a;
          mrun[r] = mn;
        }
      }
#pragma unroll
      for (int fi = 0; fi < 4; fi++) {
        int icol = fi * 16 + (l & 15);
#pragma unroll
        for (int r = 0; r < 4; r++) {
          float p = __expf(sacc[fi][r] - mrun[r]);
          lsum[r] += p;
          int jl = ((l >> 4) << 2) + r;
          int slot = (icol >> 3) ^ (jl & 7);
          myPs[jl * 64 + slot * 8 + (icol & 7)] = (bf16)p;
        }
      }
      bf16x8 pa[2];
      {
        int jl = l & 15;
#pragma unroll
        for (int kc = 0; kc < 2; kc++)
          pa[kc] = *(const bf16x8*)(myPs + jl * 64 + (((kc * 4 + (l >> 4)) ^ (jl & 7)) << 3));
      }
      __builtin_amdgcn_s_setprio(1);
#pragma unroll
      for (int fd = 0; fd < 4; fd++) {
        int row = fd * 16 + (l & 15);
#pragma unroll
        for (int kc = 0; kc < 2; kc++) {
          bf16x8 vf = *(const bf16x8*)(Vc + row * 64 + (((kc * 4 + (l >> 4)) ^ (row & 7)) << 3));
          tacc[fd] = mfma16(pa[kc], vf, tacc[fd]);
        }
      }
      __builtin_amdgcn_s_setprio(0);
    }
    asm volatile("s_waitcnt vmcnt(0)" ::: "memory");  // prefetch landed
    __syncthreads();
  }
#undef STAGE
#pragma unroll
  for (int r = 0; r < 4; r++) {
    lsum[r] += __shfl_xor(lsum[r], 1);
    lsum[r] += __shfl_xor(lsum[r], 2);
    lsum[r] += __shfl_xor(lsum[r], 4);
    lsum[r] += __shfl_xor(lsum[r], 8);
  }
#pragma unroll
  for (int r = 0; r < 4; r++) {
    int j = j0 + ((l >> 4) << 2) + r;
    float inv = 1.0f / lsum[r];
#pragma unroll
    for (int fd = 0; fd < 4; fd++) {
      int d = fd * 16 + (l & 15);
      tT[bT + (size_t)j * E_ + h * 64 + d] = (bf16)(tacc[fd][r] * inv);
    }
  }
}

extern "C" void kernel_launch(void* const* d_in, const int* in_sizes, int n_in,
                              void* d_out, int out_size, void* d_ws, size_t ws_size,
                              hipStream_t stream) {
  const float* x     = (const float*)d_in[0];
  const float* Wqkv  = (const float*)d_in[1];
  const float* Wproj = (const float*)d_in[2];
  const float* bias  = (const float*)d_in[3];
  float* out = (float*)d_out;
  char* ws = (char*)d_ws;
  bf16* Wt_qkv  = (bf16*)ws;                         // 2 MB
  bf16* Wt_proj = (bf16*)(ws + (2ull << 20));        // 2 MB
  bf16* xT      = (bf16*)(ws + (4ull << 20));        // 16 MB (reused as tT)
  bf16* kqvT    = (bf16*)(ws + (20ull << 20));       // 16 MB
  bf16* kqvD    = (bf16*)(ws + (36ull << 20));       // 16 MB  -> total 52 MB
  bf16* tT      = xT;                                // alias: xT dead after gemm1

  wconv<<<dim3(32, 32, 2), 256, 0, stream>>>(Wqkv, Wproj, Wt_qkv, Wt_proj);
  tconv<<<dim3(32, 64, B_), 256, 0, stream>>>(x, xT, E_, L_);
  gemm_bt<0><<<dim3(8, 16, B_), 256, 0, stream>>>(Wt_qkv, xT, kqvT, kqvD,
                                                  (float*)nullptr, (const float*)nullptr);
  attn<<<dim3(16, 16, B_), 512, 0, stream>>>(kqvT, kqvD, tT);
  gemm_bt<1><<<dim3(8, 16, B_), 256, 0, stream>>>(Wt_proj, tT, (bf16*)nullptr,
                                                  (bf16*)nullptr, out, bias);
}